// Round 8
// baseline (1530.838 us; speedup 1.0000x reference)
//
#include <hip/hip_runtime.h>

#define KK 50000
#define EE 128
#define HH 512
#define DIN 513

typedef short bh8 __attribute__((ext_vector_type(8)));
typedef float fx16 __attribute__((ext_vector_type(16)));

__device__ __forceinline__ short f2b(float f) {
  unsigned u = __float_as_uint(f);
  u = u + 0x7fffu + ((u >> 16) & 1u);
  return (short)(u >> 16);
}
__device__ __forceinline__ float b2f(short b) {
  return __uint_as_float(((unsigned)(unsigned short)b) << 16);
}
__device__ __forceinline__ float sigm(float x) { return 1.f / (1.f + __expf(-x)); }
__device__ __forceinline__ float tanh_(float x) {
  float ax = fabsf(x);
  float e = __expf(-2.f * ax);
  float t = (1.f - e) / (1.f + e);
  return copysignf(t, x);
}

// alpha[r] = dot(km[r,:], o_e) ; 16 lanes per row, 8 f32 each
__global__ void k_alpha(const float* __restrict__ km, const float* __restrict__ oe,
                        float* __restrict__ alpha) {
  int t = blockIdx.x * 256 + threadIdx.x;
  int r = t >> 4, j = t & 15;
  if (r >= KK) return;
  const float4* p = (const float4*)(km + (size_t)r * EE + j * 8);
  const float4* q = (const float4*)(oe + j * 8);
  float4 a0 = p[0], a1 = p[1], b0 = q[0], b1 = q[1];
  float s = a0.x * b0.x + a0.y * b0.y + a0.z * b0.z + a0.w * b0.w
          + a1.x * b1.x + a1.y * b1.y + a1.z * b1.z + a1.w * b1.w;
  s += __shfl_xor(s, 1); s += __shfl_xor(s, 2);
  s += __shfl_xor(s, 4); s += __shfl_xor(s, 8);
  if (j == 0) alpha[r] = s;
}

// Pack W_hh f32 [1536][512] -> bf16 bp[(g*64+cb)*512 + n][8]
__global__ void k_wpack(const float* __restrict__ whh, short* __restrict__ bp) {
  int o = blockIdx.x * 256 + threadIdx.x;  // < 98304
  int n = o & 511;
  int gk = o >> 9;
  int g = gk >> 6, cb = gk & 63;
  const float* src = whh + ((size_t)(g * 512 + n)) * 512 + cb * 8;
  float4 f0 = *(const float4*)src;
  float4 f1 = *(const float4*)(src + 4);
  bh8 w;
  w[0] = f2b(f0.x); w[1] = f2b(f0.y); w[2] = f2b(f0.z); w[3] = f2b(f0.w);
  w[4] = f2b(f1.x); w[5] = f2b(f1.y); w[6] = f2b(f1.z); w[7] = f2b(f1.w);
  *(bh8*)(bp + (size_t)o * 8) = w;
}

// gix[j] = dot(W_ih[j,:], concat(ex_e, s)); also zero hkp.
__global__ void k_gix(const float* __restrict__ wih, const float* __restrict__ exe,
                      const float* __restrict__ sv, float* __restrict__ gix,
                      float* __restrict__ hkp) {
  int t = threadIdx.x;
  if (blockIdx.x < 2) hkp[blockIdx.x * 256 + t] = 0.f;
  int w = blockIdx.x * 4 + (t >> 6);
  int lane = t & 63;
  float s1 = sv[0];
  float sum = 0.f;
  for (int d = lane; d < DIN; d += 64) {
    float xv = (d < 512) ? exe[d] : s1;
    sum += wih[(size_t)w * DIN + d] * xv;
  }
  sum += __shfl_xor(sum, 1); sum += __shfl_xor(sum, 2);
  sum += __shfl_xor(sum, 4); sum += __shfl_xor(sum, 8);
  sum += __shfl_xor(sum, 16); sum += __shfl_xor(sum, 32);
  if (lane == 0) gix[w] = sum;
}

// parallel softmax stage 1: per-block max + sum(exp(a-max)); 98 blocks x 512
__global__ void k_amax(const float* __restrict__ alpha, float* __restrict__ pmax,
                       float* __restrict__ psum) {
  __shared__ float rm[8], rs[8];
  int t = threadIdx.x;
  int i = blockIdx.x * 512 + t;
  float a = (i < KK) ? alpha[i] : -1e30f;
  float m = a;
  for (int o = 1; o < 64; o <<= 1) m = fmaxf(m, __shfl_xor(m, o));
  if ((t & 63) == 0) rm[t >> 6] = m;
  __syncthreads();
  if (t == 0) { float mm = rm[0]; for (int j = 1; j < 8; ++j) mm = fmaxf(mm, rm[j]); rm[0] = mm; }
  __syncthreads();
  float M = rm[0];
  float e = (i < KK) ? __expf(a - M) : 0.f;
  for (int o = 1; o < 64; o <<= 1) e += __shfl_xor(e, o);
  if ((t & 63) == 0) rs[t >> 6] = e;
  __syncthreads();
  if (t == 0) {
    float ss = 0.f;
    for (int j = 0; j < 8; ++j) ss += rs[j];
    pmax[blockIdx.x] = M; psum[blockIdx.x] = ss;
  }
}

// parallel softmax stage 2: combine 98 partials -> stat = {M, 1/S}
__global__ void k_afin(const float* __restrict__ pmax, const float* __restrict__ psum,
                       float* __restrict__ stat) {
  __shared__ float r2[2][2];
  int t = threadIdx.x;  // 128
  float m = (t < 98) ? pmax[t] : -1e30f;
  for (int o = 1; o < 64; o <<= 1) m = fmaxf(m, __shfl_xor(m, o));
  if ((t & 63) == 0) r2[0][t >> 6] = m;
  __syncthreads();
  float M = fmaxf(r2[0][0], r2[0][1]);
  float sv = (t < 98) ? psum[t] * __expf(pmax[t] - M) : 0.f;
  for (int o = 1; o < 64; o <<= 1) sv += __shfl_xor(sv, o);
  if ((t & 63) == 0) r2[1][t >> 6] = sv;
  __syncthreads();
  if (t == 0) { stat[0] = M; stat[1] = 1.f / (r2[1][0] + r2[1][1]); }
}

// h f32 -> bf16 MFMA-fragment layout hp[b64][ko 0..63][r 0..63][8]; + hkp atomics.
// 782 blocks x 512 thr, 64 rows each, 2 blocks/CU.
__global__ __launch_bounds__(512, 2) void k_hpack(
    const float* __restrict__ h, const float* __restrict__ alpha,
    const float* __restrict__ stat, short* __restrict__ hp, float* __restrict__ hkp) {
  __shared__ short Ab[64 * 520];  // [ko][r][8], stride 520
  __shared__ float hk[512];
  __shared__ float Lb[64];
  const int t = threadIdx.x, kb = t & 63, wid = t >> 6;
  const int r0 = blockIdx.x * 64;
  hk[t] = 0.f;
  if (t < 64) {
    int gr = r0 + t;
    Lb[t] = (gr < KK) ? __expf(alpha[gr] - stat[0]) * stat[1] : 0.f;
  }
  __syncthreads();
  float hp8[8] = {0.f, 0.f, 0.f, 0.f, 0.f, 0.f, 0.f, 0.f};
  #pragma unroll 2
  for (int pass = 0; pass < 8; ++pass) {
    const int r = pass * 8 + wid;
    const int gr = r0 + r;
    float v[8];
    if (gr < KK) {
      const float4* p = (const float4*)(h + (size_t)gr * HH + kb * 8);
      float4 x0 = p[0], x1 = p[1];
      v[0] = x0.x; v[1] = x0.y; v[2] = x0.z; v[3] = x0.w;
      v[4] = x1.x; v[5] = x1.y; v[6] = x1.z; v[7] = x1.w;
    } else {
      #pragma unroll
      for (int j = 0; j < 8; ++j) v[j] = 0.f;
    }
    const float bv = Lb[r];
    bh8 w;
    #pragma unroll
    for (int j = 0; j < 8; ++j) { hp8[j] += bv * v[j]; w[j] = f2b(v[j]); }
    *(bh8*)&Ab[kb * 520 + r * 8] = w;
  }
  __syncthreads();
  #pragma unroll
  for (int j = 0; j < 8; ++j) atomicAdd(&hk[kb * 8 + j], hp8[j]);
  __syncthreads();
  atomicAdd(&hkp[t], hk[t]);
  // dump LDS -> global, coalesced 16B/lane
  short* dst = hp + (size_t)blockIdx.x * 32768;
  #pragma unroll
  for (int i = 0; i < 8; ++i) {
    const int f = i * 512 + t;          // octet index 0..4095
    const int ko = f >> 6, r = f & 63;
    bh8 v = *(const bh8*)&Ab[ko * 520 + r * 8];
    *(bh8*)&dst[(size_t)f * 8] = v;
  }
}

// Fused GEMM+GRU. BM=128, 512 thr (8 waves = 4m x 2n), wave 32r x 32c x 3g,
// mfma_f32_32x32x16_bf16. NO A-panel in LDS: A-frags are coalesced 16B/lane
// global loads from hp (depth-2 register prefetch). B: 4-buffer ring of 12 KB
// K32 chunks via global_load_lds, depth-3, counted vmcnt, raw s_barrier.
// LDS = 48.5 KB -> 2 blocks/CU (4 waves/SIMD). 128 phases = 8 ni x 16 K32.
__global__ __launch_bounds__(512, 4) void k_gemm(
    const short* __restrict__ hp, const float* __restrict__ alpha,
    const float* __restrict__ stat, const float* __restrict__ gix,
    const float* __restrict__ b_ih, const float* __restrict__ b_hh,
    const short* __restrict__ bp, float* __restrict__ out) {
  __shared__ short Bbuf[4][6144];  // 49,152 B
  __shared__ float Lbeta[128];
  const int t = threadIdx.x;
  const int wid = t >> 6, lane = t & 63, l31 = lane & 31, lh = lane >> 5;
  const int wm = wid >> 1, wn = wid & 1;
  const int r0 = blockIdx.x * 128;
  if (t < 128) {
    int gr = r0 + t;
    Lbeta[t] = (gr < KK) ? __expf(alpha[gr] - stat[0]) * stat[1] : 0.f;
  }
  const short* hpb = hp + (((size_t)(2u * blockIdx.x + (wm >> 1))) << 15);
  const int arow = ((wm & 1) * 32 + l31) * 8;
  float* out1 = out + 1;

  auto STAGE = [&](int c) {
    if (t < 384) {
      const int nic = (c >> 4) & 7, phc = c & 15, buf = c & 3;
      #pragma unroll
      for (int half = 0; half < 2; ++half) {
        const int slot = t + half * 384;
        const int g = slot >> 8, rem = slot & 255;
        const int oo = rem >> 6, cc = rem & 63;
        const short* src = bp + (((size_t)(g * 64 + phc * 4 + oo)) * 512 + nic * 64 + cc) * 8;
        __builtin_amdgcn_global_load_lds(
            (const __attribute__((address_space(1))) void*)src,
            (__attribute__((address_space(3))) void*)&Bbuf[buf][slot * 8], 16, 0, 0);
      }
    }
  };
  #define LDA(PHK, KCL) (*(const bh8*)(hpb + ((PHK) * 4 + 2 * (KCL) + lh) * 512 + arow))

  fx16 acc0, acc1, acc2;
  bh8 aC0, aC1, aM0, aM1;
  float hov[16];

  STAGE(0);
  aC0 = LDA(0, 0); aC1 = LDA(0, 1);
  STAGE(1);
  aM0 = LDA(1, 0); aM1 = LDA(1, 1);
  STAGE(2);
  if (wid < 6) asm volatile("s_waitcnt vmcnt(4)" ::: "memory");
  else         asm volatile("s_waitcnt vmcnt(2)" ::: "memory");
  asm volatile("s_waitcnt lgkmcnt(0)" ::: "memory");
  asm volatile("s_barrier" ::: "memory");

  for (int ni = 0; ni < 8; ++ni) {
    #pragma unroll
    for (int q = 0; q < 16; ++q) { acc0[q] = 0.f; acc1[q] = 0.f; acc2[q] = 0.f; }
    #pragma unroll
    for (int ph = 0; ph < 16; ++ph) {
      const int p = ni * 16 + ph;
      STAGE((p + 3) & 127);
      bh8 aN0 = LDA((ph + 2) & 15, 0);
      bh8 aN1 = LDA((ph + 2) & 15, 1);
      const int buf = p & 3;
      __builtin_amdgcn_s_setprio(1);
      {
        const int bc = (wn * 32 + l31) * 8;
        bh8 b0r = *(const bh8*)&Bbuf[buf][lh * 512 + bc];
        bh8 b0z = *(const bh8*)&Bbuf[buf][lh * 512 + bc + 2048];
        bh8 b0n = *(const bh8*)&Bbuf[buf][lh * 512 + bc + 4096];
        acc0 = __builtin_amdgcn_mfma_f32_32x32x16_bf16(aC0, b0r, acc0, 0, 0, 0);
        acc1 = __builtin_amdgcn_mfma_f32_32x32x16_bf16(aC0, b0z, acc1, 0, 0, 0);
        acc2 = __builtin_amdgcn_mfma_f32_32x32x16_bf16(aC0, b0n, acc2, 0, 0, 0);
        bh8 b1r = *(const bh8*)&Bbuf[buf][(2 + lh) * 512 + bc];
        bh8 b1z = *(const bh8*)&Bbuf[buf][(2 + lh) * 512 + bc + 2048];
        bh8 b1n = *(const bh8*)&Bbuf[buf][(2 + lh) * 512 + bc + 4096];
        acc0 = __builtin_amdgcn_mfma_f32_32x32x16_bf16(aC1, b1r, acc0, 0, 0, 0);
        acc1 = __builtin_amdgcn_mfma_f32_32x32x16_bf16(aC1, b1z, acc1, 0, 0, 0);
        acc2 = __builtin_amdgcn_mfma_f32_32x32x16_bf16(aC1, b1n, acc2, 0, 0, 0);
      }
      __builtin_amdgcn_s_setprio(0);
      if (ph == 13) {
        // prefetch h_old (bf16, from hp) for the ni epilogue
        const int colq = ni * 64 + wn * 32 + l31;
        const int koq = colq >> 3, c7q = colq & 7;
        #pragma unroll
        for (int q = 0; q < 16; ++q) {
          const int rr = (wm & 1) * 32 + 4 * lh + (q & 3) + 8 * (q >> 2);
          hov[q] = b2f(hpb[(size_t)koq * 512 + rr * 8 + c7q]);
        }
      }
      if (ph == 15) {
        const int col = ni * 64 + wn * 32 + l31;
        const float gxr = gix[col], gxz = gix[col + 512], gxn = gix[col + 1024];
        const float bir = b_ih[col], biz = b_ih[col + 512], bin = b_ih[col + 1024];
        const float bhr = b_hh[col], bhz = b_hh[col + 512], bhn = b_hh[col + 1024];
        const int lrb = wm * 32 + 4 * lh;
        #pragma unroll
        for (int q = 0; q < 16; ++q) {
          const int lr = lrb + (q & 3) + 8 * (q >> 2);
          const int gr = r0 + lr;
          if (gr < KK) {
            const float bv = Lbeta[lr];
            const float rv = sigm(acc0[q] + bv * gxr + bir + bhr);
            const float zv = sigm(acc1[q] + bv * gxz + biz + bhz);
            const float nv = tanh_(bv * gxn + bin + rv * (acc2[q] + bhn));
            out1[(size_t)gr * HH + col] = (1.f - zv) * nv + zv * hov[q];
          }
        }
      }
      aC0 = aM0; aC1 = aM1; aM0 = aN0; aM1 = aN1;
      // bottom-of-phase wait = W(ph+1); {0,1,14,15}->relaxed (stores/ho in flight)
      if (wid < 6) {
        if (ph == 15 || ph == 0 || ph == 13 || ph == 14)
          asm volatile("s_waitcnt vmcnt(20)" ::: "memory");
        else
          asm volatile("s_waitcnt vmcnt(4)" ::: "memory");
      } else {
        if (ph == 15 || ph == 0 || ph == 13 || ph == 14)
          asm volatile("s_waitcnt vmcnt(18)" ::: "memory");
        else
          asm volatile("s_waitcnt vmcnt(2)" ::: "memory");
      }
      asm volatile("s_barrier" ::: "memory");
    }
  }
  #undef LDA
}

// predict_score = score_W[0:512].ex_e + score_W[512:1024].hkp + score_b
__global__ void k_score(const float* __restrict__ sw, const float* __restrict__ sb,
                        const float* __restrict__ exe, const float* __restrict__ hkp,
                        float* __restrict__ out) {
  __shared__ float red[8];
  int t = threadIdx.x;  // 512
  float v = sw[t] * exe[t] + sw[512 + t] * hkp[t];
  for (int o = 1; o < 64; o <<= 1) v += __shfl_xor(v, o);
  if ((t & 63) == 0) red[t >> 6] = v;
  __syncthreads();
  if (t == 0) {
    float s = sb[0];
    for (int i = 0; i < 8; ++i) s += red[i];
    out[0] = s;
  }
}

extern "C" void kernel_launch(void* const* d_in, const int* in_sizes, int n_in,
                              void* d_out, int out_size, void* d_ws, size_t ws_size,
                              hipStream_t stream) {
  const float* o_e  = (const float*)d_in[0];
  const float* ex_e = (const float*)d_in[1];
  const float* s    = (const float*)d_in[2];
  const float* h    = (const float*)d_in[3];
  const float* km   = (const float*)d_in[4];
  const float* W_ih = (const float*)d_in[5];
  const float* W_hh = (const float*)d_in[6];
  const float* b_ih = (const float*)d_in[7];
  const float* b_hh = (const float*)d_in[8];
  const float* sW   = (const float*)d_in[9];
  const float* sb   = (const float*)d_in[10];
  float* out = (float*)d_out;

  float* wsf   = (float*)d_ws;
  float* alpha = wsf;              // 50000 (pad 50048)
  float* pmax  = wsf + 50048;      // 98 (pad 128)
  float* psum  = wsf + 50176;      // 98 (pad 128)
  float* stat  = wsf + 50304;      // 2 (pad 16)
  float* gix   = wsf + 50320;      // 1536
  float* hkp   = wsf + 51856;      // 512 (pad to 52416)
  short* bp    = (short*)(wsf + 52416);   // 1,572,864 B
  short* hpk   = (short*)(wsf + 445632);  // 782*32768 shorts = 51.2 MB

  k_alpha<<<3125, 256, 0, stream>>>(km, o_e, alpha);
  k_wpack<<<384, 256, 0, stream>>>(W_hh, bp);
  k_gix<<<384, 256, 0, stream>>>(W_ih, ex_e, s, gix, hkp);
  k_amax<<<98, 512, 0, stream>>>(alpha, pmax, psum);
  k_afin<<<1, 128, 0, stream>>>(pmax, psum, stat);
  k_hpack<<<782, 512, 0, stream>>>(h, alpha, stat, hpk, hkp);
  k_gemm<<<391, 512, 0, stream>>>(hpk, alpha, stat, gix, b_ih, b_hh, bp, out);
  k_score<<<1, 512, 0, stream>>>(sW, sb, ex_e, hkp, out);
}

// Round 9
// 258.683 us; speedup vs baseline: 5.9178x; 5.9178x over previous
//
#include <hip/hip_runtime.h>

#define KK 50000
#define EE 128
#define HH 512
#define DIN 513

typedef short bh8 __attribute__((ext_vector_type(8)));
typedef float fx16 __attribute__((ext_vector_type(16)));

__device__ __forceinline__ short f2b(float f) {
  unsigned u = __float_as_uint(f);
  u = u + 0x7fffu + ((u >> 16) & 1u);
  return (short)(u >> 16);
}
__device__ __forceinline__ float b2f(short b) {
  return __uint_as_float(((unsigned)(unsigned short)b) << 16);
}
__device__ __forceinline__ float sigm(float x) { return 1.f / (1.f + __expf(-x)); }
__device__ __forceinline__ float tanh_(float x) {
  float ax = fabsf(x);
  float e = __expf(-2.f * ax);
  float t = (1.f - e) / (1.f + e);
  return copysignf(t, x);
}

// alpha[r] = dot(km[r,:], o_e) ; 16 lanes per row, 8 f32 each
__global__ void k_alpha(const float* __restrict__ km, const float* __restrict__ oe,
                        float* __restrict__ alpha) {
  int t = blockIdx.x * 256 + threadIdx.x;
  int r = t >> 4, j = t & 15;
  if (r >= KK) return;
  const float4* p = (const float4*)(km + (size_t)r * EE + j * 8);
  const float4* q = (const float4*)(oe + j * 8);
  float4 a0 = p[0], a1 = p[1], b0 = q[0], b1 = q[1];
  float s = a0.x * b0.x + a0.y * b0.y + a0.z * b0.z + a0.w * b0.w
          + a1.x * b1.x + a1.y * b1.y + a1.z * b1.z + a1.w * b1.w;
  s += __shfl_xor(s, 1); s += __shfl_xor(s, 2);
  s += __shfl_xor(s, 4); s += __shfl_xor(s, 8);
  if (j == 0) alpha[r] = s;
}

// Pack W_hh f32 [1536][512] -> bf16 bp[(g*64+cb)*512 + n][8]
__global__ void k_wpack(const float* __restrict__ whh, short* __restrict__ bp) {
  int o = blockIdx.x * 256 + threadIdx.x;  // < 98304
  int n = o & 511;
  int gk = o >> 9;
  int g = gk >> 6, cb = gk & 63;
  const float* src = whh + ((size_t)(g * 512 + n)) * 512 + cb * 8;
  float4 f0 = *(const float4*)src;
  float4 f1 = *(const float4*)(src + 4);
  bh8 w;
  w[0] = f2b(f0.x); w[1] = f2b(f0.y); w[2] = f2b(f0.z); w[3] = f2b(f0.w);
  w[4] = f2b(f1.x); w[5] = f2b(f1.y); w[6] = f2b(f1.z); w[7] = f2b(f1.w);
  *(bh8*)(bp + (size_t)o * 8) = w;
}

// gix[j] = dot(W_ih[j,:], concat(ex_e, s)); also zero hkp.
__global__ void k_gix(const float* __restrict__ wih, const float* __restrict__ exe,
                      const float* __restrict__ sv, float* __restrict__ gix,
                      float* __restrict__ hkp) {
  int t = threadIdx.x;
  if (blockIdx.x < 2) hkp[blockIdx.x * 256 + t] = 0.f;
  int w = blockIdx.x * 4 + (t >> 6);
  int lane = t & 63;
  float s1 = sv[0];
  float sum = 0.f;
  for (int d = lane; d < DIN; d += 64) {
    float xv = (d < 512) ? exe[d] : s1;
    sum += wih[(size_t)w * DIN + d] * xv;
  }
  sum += __shfl_xor(sum, 1); sum += __shfl_xor(sum, 2);
  sum += __shfl_xor(sum, 4); sum += __shfl_xor(sum, 8);
  sum += __shfl_xor(sum, 16); sum += __shfl_xor(sum, 32);
  if (lane == 0) gix[w] = sum;
}

// parallel softmax stage 1: per-block max + sum(exp(a-max)); 98 blocks x 512
__global__ void k_amax(const float* __restrict__ alpha, float* __restrict__ pmax,
                       float* __restrict__ psum) {
  __shared__ float rm[8], rs[8];
  int t = threadIdx.x;
  int i = blockIdx.x * 512 + t;
  float a = (i < KK) ? alpha[i] : -1e30f;
  float m = a;
  for (int o = 1; o < 64; o <<= 1) m = fmaxf(m, __shfl_xor(m, o));
  if ((t & 63) == 0) rm[t >> 6] = m;
  __syncthreads();
  if (t == 0) { float mm = rm[0]; for (int j = 1; j < 8; ++j) mm = fmaxf(mm, rm[j]); rm[0] = mm; }
  __syncthreads();
  float M = rm[0];
  float e = (i < KK) ? __expf(a - M) : 0.f;
  for (int o = 1; o < 64; o <<= 1) e += __shfl_xor(e, o);
  if ((t & 63) == 0) rs[t >> 6] = e;
  __syncthreads();
  if (t == 0) {
    float ss = 0.f;
    for (int j = 0; j < 8; ++j) ss += rs[j];
    pmax[blockIdx.x] = M; psum[blockIdx.x] = ss;
  }
}

// parallel softmax stage 2: combine 98 partials -> stat = {M, 1/S}
__global__ void k_afin(const float* __restrict__ pmax, const float* __restrict__ psum,
                       float* __restrict__ stat) {
  __shared__ float r2[2][2];
  int t = threadIdx.x;  // 128
  float m = (t < 98) ? pmax[t] : -1e30f;
  for (int o = 1; o < 64; o <<= 1) m = fmaxf(m, __shfl_xor(m, o));
  if ((t & 63) == 0) r2[0][t >> 6] = m;
  __syncthreads();
  float M = fmaxf(r2[0][0], r2[0][1]);
  float sv = (t < 98) ? psum[t] * __expf(pmax[t] - M) : 0.f;
  for (int o = 1; o < 64; o <<= 1) sv += __shfl_xor(sv, o);
  if ((t & 63) == 0) r2[1][t >> 6] = sv;
  __syncthreads();
  if (t == 0) { stat[0] = M; stat[1] = 1.f / (r2[1][0] + r2[1][1]); }
}

// h f32 -> bf16 MFMA-fragment layout hp[b64][ko 0..63][r 0..63][8]; + hkp atomics.
__global__ __launch_bounds__(512, 2) void k_hpack(
    const float* __restrict__ h, const float* __restrict__ alpha,
    const float* __restrict__ stat, short* __restrict__ hp, float* __restrict__ hkp) {
  __shared__ short Ab[64 * 520];
  __shared__ float hk[512];
  __shared__ float Lb[64];
  const int t = threadIdx.x, kb = t & 63, wid = t >> 6;
  const int r0 = blockIdx.x * 64;
  hk[t] = 0.f;
  if (t < 64) {
    int gr = r0 + t;
    Lb[t] = (gr < KK) ? __expf(alpha[gr] - stat[0]) * stat[1] : 0.f;
  }
  __syncthreads();
  float hp8[8] = {0.f, 0.f, 0.f, 0.f, 0.f, 0.f, 0.f, 0.f};
  #pragma unroll 2
  for (int pass = 0; pass < 8; ++pass) {
    const int r = pass * 8 + wid;
    const int gr = r0 + r;
    float v[8];
    if (gr < KK) {
      const float4* p = (const float4*)(h + (size_t)gr * HH + kb * 8);
      float4 x0 = p[0], x1 = p[1];
      v[0] = x0.x; v[1] = x0.y; v[2] = x0.z; v[3] = x0.w;
      v[4] = x1.x; v[5] = x1.y; v[6] = x1.z; v[7] = x1.w;
    } else {
      #pragma unroll
      for (int j = 0; j < 8; ++j) v[j] = 0.f;
    }
    const float bv = Lb[r];
    bh8 w;
    #pragma unroll
    for (int j = 0; j < 8; ++j) { hp8[j] += bv * v[j]; w[j] = f2b(v[j]); }
    *(bh8*)&Ab[kb * 520 + r * 8] = w;
  }
  __syncthreads();
  #pragma unroll
  for (int j = 0; j < 8; ++j) atomicAdd(&hk[kb * 8 + j], hp8[j]);
  __syncthreads();
  atomicAdd(&hkp[t], hk[t]);
  short* dst = hp + (size_t)blockIdx.x * 32768;
  #pragma unroll
  for (int i = 0; i < 8; ++i) {
    const int f = i * 512 + t;
    const int ko = f >> 6, r = f & 63;
    bh8 v = *(const bh8*)&Ab[ko * 520 + r * 8];
    *(bh8*)&dst[(size_t)f * 8] = v;
  }
}

// Fused GEMM+GRU. BM=128, 512 thr (8 waves = 4m x 2n), wave 32r x 32c x 3g.
// A-frags: coalesced 16B/lane global loads from hp, depth-2 register rotation.
// B: 4-buffer LDS ring of 12 KB K32 chunks via global_load_lds, depth-3,
// counted vmcnt (mixed-stream accounting), raw s_barrier. LDS 49.7 KB ->
// 2 blocks/CU (VGPR<=128 via launch_bounds(512,2) = MIN-2-BLOCKS semantics).
__global__ __launch_bounds__(512, 2) void k_gemm(
    const short* __restrict__ hp, const float* __restrict__ alpha,
    const float* __restrict__ stat, const float* __restrict__ gix,
    const float* __restrict__ b_ih, const float* __restrict__ b_hh,
    const short* __restrict__ bp, float* __restrict__ out) {
  __shared__ short Bbuf[4][6144];  // 49,152 B
  __shared__ float Lbeta[128];
  const int t = threadIdx.x;
  const int wid = t >> 6, lane = t & 63, l31 = lane & 31, lh = lane >> 5;
  const int wm = wid >> 1, wn = wid & 1;
  const int r0 = blockIdx.x * 128;
  if (t < 128) {
    int gr = r0 + t;
    Lbeta[t] = (gr < KK) ? __expf(alpha[gr] - stat[0]) * stat[1] : 0.f;
  }
  const short* hpb = hp + (((size_t)(2u * blockIdx.x + (wm >> 1))) << 15);
  const int arow = ((wm & 1) * 32 + l31) * 8;
  float* out1 = out + 1;

  auto STAGE = [&](int c) {
    if (t < 384) {
      const int nic = (c >> 4) & 7, phc = c & 15, buf = c & 3;
      #pragma unroll
      for (int half = 0; half < 2; ++half) {
        const int slot = t + half * 384;
        const int g = slot >> 8, rem = slot & 255;
        const int oo = rem >> 6, cc = rem & 63;
        const short* src = bp + (((size_t)(g * 64 + phc * 4 + oo)) * 512 + nic * 64 + cc) * 8;
        __builtin_amdgcn_global_load_lds(
            (const __attribute__((address_space(1))) void*)src,
            (__attribute__((address_space(3))) void*)&Bbuf[buf][slot * 8], 16, 0, 0);
      }
    }
  };
  #define LDA(PHK, KCL) (*(const bh8*)(hpb + ((PHK) * 4 + 2 * (KCL) + lh) * 512 + arow))

  fx16 acc0, acc1, acc2;
  bh8 aC0, aC1, aM0, aM1;

  // prologue: A first, then stages (keeps queue shape for counted waits)
  aC0 = LDA(0, 0); aC1 = LDA(0, 1);
  aM0 = LDA(1, 0); aM1 = LDA(1, 1);
  STAGE(0); STAGE(1); STAGE(2);

  for (int ni = 0; ni < 8; ++ni) {
    #pragma unroll
    for (int q = 0; q < 16; ++q) { acc0[q] = 0.f; acc1[q] = 0.f; acc2[q] = 0.f; }
    #pragma unroll
    for (int ph = 0; ph < 16; ++ph) {
      // A prefetch for phase p+2 (issued BEFORE the wait)
      bh8 aN0 = LDA((ph + 2) & 15, 0);
      bh8 aN1 = LDA((ph + 2) & 15, 1);
      // counted wait: chunk p landed (S(p+1),A(p+1),S(p+2),A(p+2),A(p) may fly)
      if (ph == 0) {
        if (ni == 0) { asm volatile("s_waitcnt vmcnt(6)" ::: "memory"); }
        else         { asm volatile("s_waitcnt vmcnt(10)" ::: "memory"); }
      } else if (ph == 1) {
        if (ni == 0) { asm volatile("s_waitcnt vmcnt(8)" ::: "memory"); }
        else         { asm volatile("s_waitcnt vmcnt(10)" ::: "memory"); }
      } else {
        asm volatile("s_waitcnt vmcnt(10)" ::: "memory");
      }
      asm volatile("s_barrier" ::: "memory");
      STAGE((ni * 16 + ph + 3) & 127);
      __builtin_amdgcn_sched_barrier(0);
      const int buf = ph & 3;  // (ni*16+ph)&3 == ph&3
      __builtin_amdgcn_s_setprio(1);
      {
        const int bc = (wn * 32 + l31) * 8;
        bh8 b0r = *(const bh8*)&Bbuf[buf][lh * 512 + bc];
        bh8 b0z = *(const bh8*)&Bbuf[buf][lh * 512 + bc + 2048];
        bh8 b0n = *(const bh8*)&Bbuf[buf][lh * 512 + bc + 4096];
        acc0 = __builtin_amdgcn_mfma_f32_32x32x16_bf16(aC0, b0r, acc0, 0, 0, 0);
        acc1 = __builtin_amdgcn_mfma_f32_32x32x16_bf16(aC0, b0z, acc1, 0, 0, 0);
        acc2 = __builtin_amdgcn_mfma_f32_32x32x16_bf16(aC0, b0n, acc2, 0, 0, 0);
        bh8 b1r = *(const bh8*)&Bbuf[buf][(2 + lh) * 512 + bc];
        bh8 b1z = *(const bh8*)&Bbuf[buf][(2 + lh) * 512 + bc + 2048];
        bh8 b1n = *(const bh8*)&Bbuf[buf][(2 + lh) * 512 + bc + 4096];
        acc0 = __builtin_amdgcn_mfma_f32_32x32x16_bf16(aC1, b1r, acc0, 0, 0, 0);
        acc1 = __builtin_amdgcn_mfma_f32_32x32x16_bf16(aC1, b1z, acc1, 0, 0, 0);
        acc2 = __builtin_amdgcn_mfma_f32_32x32x16_bf16(aC1, b1n, acc2, 0, 0, 0);
      }
      __builtin_amdgcn_s_setprio(0);
      if (ph == 15) {
        __builtin_amdgcn_sched_barrier(0);
        const int col = ni * 64 + wn * 32 + l31;
        const int koq = col >> 3, c7q = col & 7;
        const float gxr = gix[col], gxz = gix[col + 512], gxn = gix[col + 1024];
        const float bir = b_ih[col], biz = b_ih[col + 512], bin = b_ih[col + 1024];
        const float bhr = b_hh[col], bhz = b_hh[col + 512], bhn = b_hh[col + 1024];
        const int lrb = wm * 32 + 4 * lh;
        #pragma unroll
        for (int q = 0; q < 16; ++q) {
          const int lr = lrb + (q & 3) + 8 * (q >> 2);
          const int gr = r0 + lr;
          if (gr < KK) {
            const int rr = (wm & 1) * 32 + 4 * lh + (q & 3) + 8 * (q >> 2);
            const float ho = b2f(hpb[(size_t)koq * 512 + rr * 8 + c7q]);
            const float bv = Lbeta[lr];
            const float rv = sigm(acc0[q] + bv * gxr + bir + bhr);
            const float zv = sigm(acc1[q] + bv * gxz + biz + bhz);
            const float nv = tanh_(bv * gxn + bin + rv * (acc2[q] + bhn));
            out1[(size_t)gr * HH + col] = (1.f - zv) * nv + zv * ho;
          }
        }
        __builtin_amdgcn_sched_barrier(0);
      }
      aC0 = aM0; aC1 = aM1; aM0 = aN0; aM1 = aN1;
    }
  }
  #undef LDA
}

// predict_score = score_W[0:512].ex_e + score_W[512:1024].hkp + score_b
__global__ void k_score(const float* __restrict__ sw, const float* __restrict__ sb,
                        const float* __restrict__ exe, const float* __restrict__ hkp,
                        float* __restrict__ out) {
  __shared__ float red[8];
  int t = threadIdx.x;  // 512
  float v = sw[t] * exe[t] + sw[512 + t] * hkp[t];
  for (int o = 1; o < 64; o <<= 1) v += __shfl_xor(v, o);
  if ((t & 63) == 0) red[t >> 6] = v;
  __syncthreads();
  if (t == 0) {
    float s = sb[0];
    for (int i = 0; i < 8; ++i) s += red[i];
    out[0] = s;
  }
}

extern "C" void kernel_launch(void* const* d_in, const int* in_sizes, int n_in,
                              void* d_out, int out_size, void* d_ws, size_t ws_size,
                              hipStream_t stream) {
  const float* o_e  = (const float*)d_in[0];
  const float* ex_e = (const float*)d_in[1];
  const float* s    = (const float*)d_in[2];
  const float* h    = (const float*)d_in[3];
  const float* km   = (const float*)d_in[4];
  const float* W_ih = (const float*)d_in[5];
  const float* W_hh = (const float*)d_in[6];
  const float* b_ih = (const float*)d_in[7];
  const float* b_hh = (const float*)d_in[8];
  const float* sW   = (const float*)d_in[9];
  const float* sb   = (const float*)d_in[10];
  float* out = (float*)d_out;

  float* wsf   = (float*)d_ws;
  float* alpha = wsf;              // 50000 (pad 50048)
  float* pmax  = wsf + 50048;      // 98 (pad 128)
  float* psum  = wsf + 50176;      // 98 (pad 128)
  float* stat  = wsf + 50304;      // 2 (pad 16)
  float* gix   = wsf + 50320;      // 1536
  float* hkp   = wsf + 51856;      // 512 (pad to 52416)
  short* bp    = (short*)(wsf + 52416);   // 1,572,864 B
  short* hpk   = (short*)(wsf + 445632);  // 782*32768 shorts = 51.2 MB

  k_alpha<<<3125, 256, 0, stream>>>(km, o_e, alpha);
  k_wpack<<<384, 256, 0, stream>>>(W_hh, bp);
  k_gix<<<384, 256, 0, stream>>>(W_ih, ex_e, s, gix, hkp);
  k_amax<<<98, 512, 0, stream>>>(alpha, pmax, psum);
  k_afin<<<1, 128, 0, stream>>>(pmax, psum, stat);
  k_hpack<<<782, 512, 0, stream>>>(h, alpha, stat, hpk, hkp);
  k_gemm<<<391, 512, 0, stream>>>(hpk, alpha, stat, gix, b_ih, b_hh, bp, out);
  k_score<<<1, 512, 0, stream>>>(sW, sb, ex_e, hkp, out);
}